// Round 1
// baseline (41.600 us; speedup 1.0000x reference)
//
#include <hip/hip_runtime.h>
#include <math.h>

namespace {
constexpr int S  = 52;
constexpr int SS = S * S;          // 2704
constexpr int A  = 5;
constexpr int NC = 20;
constexpr int CH = 5 + NC;         // 25
constexpr int B  = 32;
constexpr int M  = 50;
constexpr int TSTRIDE = 6;         // xy(2)+wh(2)+conf(1)+cls(1)
constexpr float IGNORE_T = 0.75f;
constexpr int NBLK1 = (B * A) * ((SS + 255) / 256);   // 160*11 = 1760

__device__ __forceinline__ float sigm(float x) { return 1.0f / (1.0f + __expf(-x)); }

__device__ __forceinline__ float iou_one(float px, float py, float pw, float ph,
                                         float gx, float gy, float gw, float gh) {
  float tlx = fmaxf(px - pw * 0.5f, gx - gw * 0.5f);
  float brx = fminf(px + pw * 0.5f, gx + gw * 0.5f);
  float tly = fmaxf(py - ph * 0.5f, gy - gh * 0.5f);
  float bry = fminf(py + ph * 0.5f, gy + gh * 0.5f);
  if (tlx < brx && tly < bry) {
    float ai = (brx - tlx) * (bry - tly);
    return ai / (pw * ph + gw * gh - ai);
  }
  return 0.0f;
}

// Dense noobj iou-loss term for every (b, a, cell). One block-sum per block.
__global__ __launch_bounds__(256) void k_noobj(const float* __restrict__ outp,
                                               const float* __restrict__ targ,
                                               const float* __restrict__ anch,
                                               float* __restrict__ blocksum) {
  __shared__ float sg[M][4];
  __shared__ int   sv[M];
  const int ba  = blockIdx.x;            // b*A + a
  const int b   = ba / A, a = ba % A;
  const int tid = threadIdx.x;
  if (tid < M) {
    const float* t = targ + (size_t)(b * M + tid) * TSTRIDE;
    float t0 = t[0], t1 = t[1], t2 = t[2], t3 = t[3], t4 = t[4], t5 = t[5];
    sv[tid] = (t0 + t1 + t2 + t3 + t4 + t5) > 0.0f ? 1 : 0;
    sg[tid][0] = t0 * S; sg[tid][1] = t1 * S; sg[tid][2] = t2 * S; sg[tid][3] = t3 * S;
  }
  __syncthreads();
  const int pos = blockIdx.y * 256 + tid;
  float term = 0.0f;
  if (pos < SS) {
    const float* base = outp + (size_t)(b * A + a) * CH * SS + pos;
    float tx = base[0];
    float ty = base[SS];
    float tw = base[2 * SS];
    float th = base[3 * SS];
    float tc = base[4 * SS];
    int y = pos / S, x = pos - y * S;
    float aw = anch[2 * a], ah = anch[2 * a + 1];
    float px = sigm(tx) + (float)x;
    float py = sigm(ty) + (float)y;
    float pw = __expf(tw) * aw;
    float ph = __expf(th) * ah;
    float maxiou = 0.0f;
    for (int m = 0; m < M; ++m) {
      if (sv[m]) {
        maxiou = fmaxf(maxiou, iou_one(px, py, pw, ph,
                                       sg[m][0], sg[m][1], sg[m][2], sg[m][3]));
      }
    }
    float pc = sigm(tc);
    term = (maxiou >= IGNORE_T) ? 0.0f : pc * pc;   // (1 * pconf)^2 or 0
  }
  for (int off = 32; off > 0; off >>= 1) term += __shfl_down(term, off);
  __shared__ float wsum[4];
  int lane = tid & 63, wid = tid >> 6;
  if (lane == 0) wsum[wid] = term;
  __syncthreads();
  if (tid == 0)
    blocksum[blockIdx.y * gridDim.x + blockIdx.x] = wsum[0] + wsum[1] + wsum[2] + wsum[3];
}

// Per-GT sparse corrections: one block per batch, thread = gt index.
__global__ __launch_bounds__(64) void k_gt(const float* __restrict__ outp,
                                           const float* __restrict__ targ,
                                           const float* __restrict__ anch,
                                           float* __restrict__ corr) {
  __shared__ float sg[M][4];
  __shared__ int   sv[M];
  __shared__ int   skey[64];
  const int b = blockIdx.x;
  const int m = threadIdx.x;
  int valid = 0;
  float gx = 0, gy = 0, gw = 0, gh = 0;
  int gcls = 0, cx = 0, cy = 0, best = 0;
  float dx = 0, dy = 0, dw = 0, dh = 0;
  if (m < M) {
    const float* t = targ + (size_t)(b * M + m) * TSTRIDE;
    float t0 = t[0], t1 = t[1], t2 = t[2], t3 = t[3], t4 = t[4], t5 = t[5];
    valid = (t0 + t1 + t2 + t3 + t4 + t5) > 0.0f ? 1 : 0;
    gx = t0 * S; gy = t1 * S; gw = t2 * S; gh = t3 * S;
    gcls = (int)t5;
    sg[m][0] = gx; sg[m][1] = gy; sg[m][2] = gw; sg[m][3] = gh;
    sv[m] = valid;
  }
  if (valid) {
    cx = (int)fminf(fmaxf(floorf(gx - gw * 0.5f), 0.0f), (float)(S - 1));
    cy = (int)fminf(fmaxf(floorf(gy - gh * 0.5f), 0.0f), (float)(S - 1));
    float acx = cx + 0.5f, acy = cy + 0.5f;
    float bestv = -1.0f;
    for (int k = 0; k < A; ++k) {
      float aw = anch[2 * k], ah = anch[2 * k + 1];
      float tlx = fmaxf(acx - aw * 0.5f, gx - gw * 0.5f);
      float brx = fminf(acx + aw * 0.5f, gx + gw * 0.5f);
      float tly = fmaxf(acy - ah * 0.5f, gy - gh * 0.5f);
      float bry = fminf(acy + ah * 0.5f, gy + gh * 0.5f);
      float v = 0.0f;
      if (tlx < brx && tly < bry) {
        float ai = (brx - tlx) * (bry - tly);
        v = ai / (aw * ah + gw * gh - ai);
      }
      if (v > bestv) { bestv = v; best = k; }   // strict > == jnp.argmax first-max
    }
    dx = gx - acx; dy = gy - acy;
    dw = gw / anch[2 * best]; dh = gh / anch[2 * best + 1];
  }
  skey[m] = valid ? ((cy * S + cx) * A + best) : -1;
  __syncthreads();
  // last-write-wins: winner iff no later valid gt hits the same (cell, anchor)
  bool winner = (valid != 0);
  if (winner) {
    int key = skey[m];
    for (int mm = m + 1; mm < M; ++mm)
      if (skey[mm] == key) { winner = false; break; }
  }
  float ciou = 0.0f, cbox = 0.0f, ccls = 0.0f;
  if (winner) {
    int cell = cy * S + cx;
    const float* base = outp + (size_t)(b * A + best) * CH * SS + cell;
    float tx = base[0], ty = base[SS], tw = base[2 * SS], th = base[3 * SS], tc = base[4 * SS];
    float aw = anch[2 * best], ah = anch[2 * best + 1];
    float px = sigm(tx) + (float)cx;
    float py = sigm(ty) + (float)cy;
    float pw = __expf(tw) * aw;
    float ph = __expf(th) * ah;
    float miou = 0.0f;   // recompute max_iou at this single position
    for (int mm = 0; mm < M; ++mm)
      if (sv[mm])
        miou = fmaxf(miou, iou_one(px, py, pw, ph,
                                   sg[mm][0], sg[mm][1], sg[mm][2], sg[mm][3]));
    float pc = sigm(tc);
    float defterm = (miou >= IGNORE_T) ? 0.0f : pc * pc;
    float d5 = 5.0f * (pc - miou);                 // OBJ_SCALE = 5
    ciou = d5 * d5 - defterm;                      // replace default with obj term
    float e0 = sigm(tx) - dx;
    float e1 = sigm(ty) - dy;
    float e2 = __expf(tw) - dw;
    float e3 = __expf(th) - dh;
    cbox = e0 * e0 + e1 * e1 + e2 * e2 + e3 * e3;
    float l[NC];
    float lmax = -1e30f;
    for (int c = 0; c < NC; ++c) { l[c] = base[(5 + c) * SS]; lmax = fmaxf(lmax, l[c]); }
    float se = 0.0f;
    for (int c = 0; c < NC; ++c) se += __expf(l[c] - lmax);
    ccls = (lmax + __logf(se)) - l[gcls];          // NLL
  }
  for (int off = 32; off > 0; off >>= 1) {
    ciou += __shfl_down(ciou, off);
    cbox += __shfl_down(cbox, off);
    ccls += __shfl_down(ccls, off);
  }
  if (m == 0) {
    corr[b * 3 + 0] = ciou;
    corr[b * 3 + 1] = cbox;
    corr[b * 3 + 2] = ccls;
  }
}

__global__ __launch_bounds__(256) void k_final(const float* __restrict__ blocksum,
                                               const float* __restrict__ corr,
                                               float* __restrict__ out) {
  int tid = threadIdx.x;
  float s = 0.0f;
  for (int i = tid; i < NBLK1; i += 256) s += blocksum[i];
  for (int off = 32; off > 0; off >>= 1) s += __shfl_down(s, off);
  __shared__ float wsum[4];
  int lane = tid & 63, wid = tid >> 6;
  if (lane == 0) wsum[wid] = s;
  __syncthreads();
  if (tid == 0) {
    float siou = wsum[0] + wsum[1] + wsum[2] + wsum[3];
    float cio = 0.0f, cbx = 0.0f, ccl = 0.0f;
    for (int bb = 0; bb < B; ++bb) {
      cio += corr[bb * 3 + 0];
      cbx += corr[bb * 3 + 1];
      ccl += corr[bb * 3 + 2];
    }
    // box: COORD/(2B) = 1/64 ; iou: 1/(2B) = 1/64 ; class: CLASS/B = 1/32
    out[0] = (siou + cio + cbx) * (1.0f / 64.0f) + ccl * (1.0f / 32.0f);
  }
}

}  // namespace

extern "C" void kernel_launch(void* const* d_in, const int* in_sizes, int n_in,
                              void* d_out, int out_size, void* d_ws, size_t ws_size,
                              hipStream_t stream) {
  const float* outp = (const float*)d_in[0];
  const float* targ = (const float*)d_in[1];
  const float* anch = (const float*)d_in[2];
  float* ws = (float*)d_ws;
  float* blocksum = ws;            // NBLK1 floats, fully rewritten each call
  float* corr = ws + NBLK1;        // B*3 floats, fully rewritten each call

  dim3 g1(B * A, (SS + 255) / 256);
  k_noobj<<<g1, 256, 0, stream>>>(outp, targ, anch, blocksum);
  k_gt<<<B, 64, 0, stream>>>(outp, targ, anch, corr);
  k_final<<<1, 256, 0, stream>>>(blocksum, corr, (float*)d_out);
}

// Round 2
// 39.905 us; speedup vs baseline: 1.0425x; 1.0425x over previous
//
#include <hip/hip_runtime.h>
#include <math.h>

namespace {
constexpr int S  = 52;
constexpr int SS = S * S;          // 2704
constexpr int A  = 5;
constexpr int NC = 20;
constexpr int CH = 5 + NC;         // 25
constexpr int B  = 32;
constexpr int M  = 50;
constexpr int TSTRIDE = 6;         // xy(2)+wh(2)+conf(1)+cls(1)
constexpr float IGNORE_T = 0.75f;

constexpr int POS_PER_T = 4;
constexpr int CHUNK = 256 * POS_PER_T;                 // 1024 positions per block
constexpr int NBY = (SS + CHUNK - 1) / CHUNK;          // 3
constexpr int NBLK1 = (B * A) * NBY;                   // 480

__device__ __forceinline__ float sigm(float x) { return 1.0f / (1.0f + __expf(-x)); }

__device__ __forceinline__ float iou_one(float px, float py, float pw, float ph,
                                         float gx, float gy, float gw, float gh) {
  float tlx = fmaxf(px - pw * 0.5f, gx - gw * 0.5f);
  float brx = fminf(px + pw * 0.5f, gx + gw * 0.5f);
  float tly = fmaxf(py - ph * 0.5f, gy - gh * 0.5f);
  float bry = fminf(py + ph * 0.5f, gy + gh * 0.5f);
  if (tlx < brx && tly < bry) {
    float ai = (brx - tlx) * (bry - tly);
    return ai / (pw * ph + gw * gh - ai);
  }
  return 0.0f;
}

// Dense noobj iou-loss term. Division-free ignore test:
//   iou >= 0.75  <=>  1.75*ai >= 0.75*(pa+ga)   (union > 0 always)
__global__ __launch_bounds__(256) void k_noobj(const float* __restrict__ outp,
                                               const float* __restrict__ targ,
                                               const float* __restrict__ anch,
                                               float* __restrict__ blocksum) {
  __shared__ float4 sgc[M];   // gt corners: tlx, tly, brx, bry
  __shared__ float  sga[M];   // 0.75 * gt area
  const int ba  = blockIdx.x;            // b*A + a
  const int b   = ba / A, a = ba % A;
  const int tid = threadIdx.x;
  if (tid < M) {
    const float* t = targ + (size_t)(b * M + tid) * TSTRIDE;
    float t0 = t[0], t1 = t[1], t2 = t[2], t3 = t[3], t4 = t[4], t5 = t[5];
    bool valid = (t0 + t1 + t2 + t3 + t4 + t5) > 0.0f;
    float gx = t0 * S, gy = t1 * S, gw = t2 * S, gh = t3 * S;
    float4 c;
    float ga;
    if (valid) {
      c = make_float4(gx - gw * 0.5f, gy - gh * 0.5f, gx + gw * 0.5f, gy + gh * 0.5f);
      ga = 0.75f * gw * gh;
    } else {
      c = make_float4(1e30f, 1e30f, -1e30f, -1e30f);   // degenerate -> never hits
      ga = 0.0f;
    }
    sgc[tid] = c;
    sga[tid] = ga;
  }
  __syncthreads();

  const float aw = anch[2 * a], ah = anch[2 * a + 1];
  const float* base = outp + (size_t)ba * CH * SS;
  const int pos0 = blockIdx.y * CHUNK + tid;

  float ptlx[POS_PER_T], ptly[POS_PER_T], pbrx[POS_PER_T], pbry[POS_PER_T];
  float rhsb[POS_PER_T], pcsq[POS_PER_T];
#pragma unroll
  for (int k = 0; k < POS_PER_T; ++k) {
    int pos = pos0 + k * 256;
    bool act = pos < SS;
    int p = act ? pos : 0;
    float tx = base[p];
    float ty = base[p + SS];
    float tw = base[p + 2 * SS];
    float th = base[p + 3 * SS];
    float tc = base[p + 4 * SS];
    int y = p / S, x = p - y * S;
    float px = sigm(tx) + (float)x;
    float py = sigm(ty) + (float)y;
    float pw = __expf(tw) * aw;
    float ph = __expf(th) * ah;
    ptlx[k] = px - pw * 0.5f;
    ptly[k] = py - ph * 0.5f;
    pbrx[k] = px + pw * 0.5f;
    pbry[k] = py + ph * 0.5f;
    rhsb[k] = 0.75f * (pw * ph);
    float pc = sigm(tc);
    pcsq[k] = act ? pc * pc : 0.0f;
  }

  int covered = 0;   // bit k set => max_iou >= IGNORE_T for position k
  for (int m = 0; m < M; ++m) {
    float4 g = sgc[m];
    float ga = sga[m];
#pragma unroll
    for (int k = 0; k < POS_PER_T; ++k) {
      float tlx = fmaxf(ptlx[k], g.x);
      float tly = fmaxf(ptly[k], g.y);
      float brx = fminf(pbrx[k], g.z);
      float bry = fminf(pbry[k], g.w);
      float dx = brx - tlx;
      float dy = bry - tly;
      float ai = dx * dy;
      bool hit = (dx > 0.0f) & (dy > 0.0f) & (1.75f * ai >= rhsb[k] + ga);
      covered |= (hit ? 1 : 0) << k;
    }
  }

  float term = 0.0f;
#pragma unroll
  for (int k = 0; k < POS_PER_T; ++k)
    term += (covered >> k & 1) ? 0.0f : pcsq[k];

  for (int off = 32; off > 0; off >>= 1) term += __shfl_down(term, off);
  __shared__ float wsum[4];
  int lane = tid & 63, wid = tid >> 6;
  if (lane == 0) wsum[wid] = term;
  __syncthreads();
  if (tid == 0)
    blocksum[blockIdx.y * gridDim.x + blockIdx.x] = wsum[0] + wsum[1] + wsum[2] + wsum[3];
}

// Per-GT sparse corrections: one block per batch, thread = gt index.
__global__ __launch_bounds__(64) void k_gt(const float* __restrict__ outp,
                                           const float* __restrict__ targ,
                                           const float* __restrict__ anch,
                                           float* __restrict__ corr) {
  __shared__ float sg[M][4];
  __shared__ int   sv[M];
  __shared__ int   skey[64];
  const int b = blockIdx.x;
  const int m = threadIdx.x;
  int valid = 0;
  float gx = 0, gy = 0, gw = 0, gh = 0;
  int gcls = 0, cx = 0, cy = 0, best = 0;
  float dx = 0, dy = 0, dw = 0, dh = 0;
  if (m < M) {
    const float* t = targ + (size_t)(b * M + m) * TSTRIDE;
    float t0 = t[0], t1 = t[1], t2 = t[2], t3 = t[3], t4 = t[4], t5 = t[5];
    valid = (t0 + t1 + t2 + t3 + t4 + t5) > 0.0f ? 1 : 0;
    gx = t0 * S; gy = t1 * S; gw = t2 * S; gh = t3 * S;
    gcls = (int)t5;
    sg[m][0] = gx; sg[m][1] = gy; sg[m][2] = gw; sg[m][3] = gh;
    sv[m] = valid;
  }
  if (valid) {
    cx = (int)fminf(fmaxf(floorf(gx - gw * 0.5f), 0.0f), (float)(S - 1));
    cy = (int)fminf(fmaxf(floorf(gy - gh * 0.5f), 0.0f), (float)(S - 1));
    float acx = cx + 0.5f, acy = cy + 0.5f;
    float bestv = -1.0f;
    for (int k = 0; k < A; ++k) {
      float aw = anch[2 * k], ah = anch[2 * k + 1];
      float tlx = fmaxf(acx - aw * 0.5f, gx - gw * 0.5f);
      float brx = fminf(acx + aw * 0.5f, gx + gw * 0.5f);
      float tly = fmaxf(acy - ah * 0.5f, gy - gh * 0.5f);
      float bry = fminf(acy + ah * 0.5f, gy + gh * 0.5f);
      float v = 0.0f;
      if (tlx < brx && tly < bry) {
        float ai = (brx - tlx) * (bry - tly);
        v = ai / (aw * ah + gw * gh - ai);
      }
      if (v > bestv) { bestv = v; best = k; }   // strict > == jnp.argmax first-max
    }
    dx = gx - acx; dy = gy - acy;
    dw = gw / anch[2 * best]; dh = gh / anch[2 * best + 1];
  }
  skey[m] = valid ? ((cy * S + cx) * A + best) : -1;
  __syncthreads();
  // last-write-wins: winner iff no later valid gt hits the same (cell, anchor)
  bool winner = (valid != 0);
  if (winner) {
    int key = skey[m];
    for (int mm = m + 1; mm < M; ++mm)
      if (skey[mm] == key) { winner = false; break; }
  }
  float ciou = 0.0f, cbox = 0.0f, ccls = 0.0f;
  if (winner) {
    int cell = cy * S + cx;
    const float* base = outp + (size_t)(b * A + best) * CH * SS + cell;
    float tx = base[0], ty = base[SS], tw = base[2 * SS], th = base[3 * SS], tc = base[4 * SS];
    float aw = anch[2 * best], ah = anch[2 * best + 1];
    float px = sigm(tx) + (float)cx;
    float py = sigm(ty) + (float)cy;
    float pw = __expf(tw) * aw;
    float ph = __expf(th) * ah;
    float miou = 0.0f;   // recompute max_iou at this single position
    for (int mm = 0; mm < M; ++mm)
      if (sv[mm])
        miou = fmaxf(miou, iou_one(px, py, pw, ph,
                                   sg[mm][0], sg[mm][1], sg[mm][2], sg[mm][3]));
    float pc = sigm(tc);
    float defterm = (miou >= IGNORE_T) ? 0.0f : pc * pc;
    float d5 = 5.0f * (pc - miou);                 // OBJ_SCALE = 5
    ciou = d5 * d5 - defterm;                      // replace default with obj term
    float e0 = sigm(tx) - dx;
    float e1 = sigm(ty) - dy;
    float e2 = __expf(tw) - dw;
    float e3 = __expf(th) - dh;
    cbox = e0 * e0 + e1 * e1 + e2 * e2 + e3 * e3;
    float l[NC];
    float lmax = -1e30f;
    for (int c = 0; c < NC; ++c) { l[c] = base[(5 + c) * SS]; lmax = fmaxf(lmax, l[c]); }
    float se = 0.0f;
    for (int c = 0; c < NC; ++c) se += __expf(l[c] - lmax);
    ccls = (lmax + __logf(se)) - l[gcls];          // NLL
  }
  for (int off = 32; off > 0; off >>= 1) {
    ciou += __shfl_down(ciou, off);
    cbox += __shfl_down(cbox, off);
    ccls += __shfl_down(ccls, off);
  }
  if (m == 0) {
    corr[b * 3 + 0] = ciou;
    corr[b * 3 + 1] = cbox;
    corr[b * 3 + 2] = ccls;
  }
}

__global__ __launch_bounds__(256) void k_final(const float* __restrict__ blocksum,
                                               const float* __restrict__ corr,
                                               float* __restrict__ out) {
  int tid = threadIdx.x;
  float s = 0.0f;
  for (int i = tid; i < NBLK1; i += 256) s += blocksum[i];
  for (int off = 32; off > 0; off >>= 1) s += __shfl_down(s, off);
  __shared__ float wsum[4];
  int lane = tid & 63, wid = tid >> 6;
  if (lane == 0) wsum[wid] = s;
  __syncthreads();
  if (tid == 0) {
    float siou = wsum[0] + wsum[1] + wsum[2] + wsum[3];
    float cio = 0.0f, cbx = 0.0f, ccl = 0.0f;
    for (int bb = 0; bb < B; ++bb) {
      cio += corr[bb * 3 + 0];
      cbx += corr[bb * 3 + 1];
      ccl += corr[bb * 3 + 2];
    }
    // box: COORD/(2B) = 1/64 ; iou: 1/(2B) = 1/64 ; class: CLASS/B = 1/32
    out[0] = (siou + cio + cbx) * (1.0f / 64.0f) + ccl * (1.0f / 32.0f);
  }
}

}  // namespace

extern "C" void kernel_launch(void* const* d_in, const int* in_sizes, int n_in,
                              void* d_out, int out_size, void* d_ws, size_t ws_size,
                              hipStream_t stream) {
  const float* outp = (const float*)d_in[0];
  const float* targ = (const float*)d_in[1];
  const float* anch = (const float*)d_in[2];
  float* ws = (float*)d_ws;
  float* blocksum = ws;            // NBLK1 floats, fully rewritten each call
  float* corr = ws + NBLK1;        // B*3 floats, fully rewritten each call

  dim3 g1(B * A, NBY);
  k_noobj<<<g1, 256, 0, stream>>>(outp, targ, anch, blocksum);
  k_gt<<<B, 64, 0, stream>>>(outp, targ, anch, corr);
  k_final<<<1, 256, 0, stream>>>(blocksum, corr, (float*)d_out);
}

// Round 3
// 35.662 us; speedup vs baseline: 1.1665x; 1.1190x over previous
//
#include <hip/hip_runtime.h>
#include <math.h>

namespace {
constexpr int S  = 52;
constexpr int SS = S * S;          // 2704
constexpr int A  = 5;
constexpr int NC = 20;
constexpr int CH = 5 + NC;         // 25
constexpr int B  = 32;
constexpr int M  = 50;
constexpr int TSTRIDE = 6;         // xy(2)+wh(2)+conf(1)+cls(1)
constexpr float IGNORE_T = 0.75f;

constexpr int POS_PER_T = 4;
constexpr int CHUNK = 256 * POS_PER_T;                 // 1024 positions per block
constexpr int NBY = (SS + CHUNK - 1) / CHUNK;          // 3
constexpr int NBA = B * A;                             // 160
constexpr int NBLK_NOOBJ = NBA * NBY;                  // 480
constexpr int NBLK = NBLK_NOOBJ + B;                   // 512 total blocks

__device__ __forceinline__ float sigm(float x) { return 1.0f / (1.0f + __expf(-x)); }

__device__ __forceinline__ float iou_one(float px, float py, float pw, float ph,
                                         float gx, float gy, float gw, float gh) {
  float tlx = fmaxf(px - pw * 0.5f, gx - gw * 0.5f);
  float brx = fminf(px + pw * 0.5f, gx + gw * 0.5f);
  float tly = fmaxf(py - ph * 0.5f, gy - gh * 0.5f);
  float bry = fminf(py + ph * 0.5f, gy + gh * 0.5f);
  if (tlx < brx && tly < bry) {
    float ai = (brx - tlx) * (bry - tly);
    return ai / (pw * ph + gw * gh - ai);
  }
  return 0.0f;
}

// One kernel: blocks [0, NBLK_NOOBJ) do the dense noobj term, blocks
// [NBLK_NOOBJ, NBLK) do per-GT sparse corrections, and the LAST block to
// finish (atomic counter) reduces all partials and writes the scalar loss.
__global__ __launch_bounds__(256) void k_fused(const float* __restrict__ outp,
                                               const float* __restrict__ targ,
                                               const float* __restrict__ anch,
                                               int* __restrict__ counter,
                                               float* __restrict__ blocksum,
                                               float* __restrict__ corr,
                                               float* __restrict__ out) {
  __shared__ float4 sgc[M];
  __shared__ float  sga[M];
  __shared__ float  sg[M][4];
  __shared__ int    sv[M];
  __shared__ int    skey[64];
  __shared__ float  wsum[4];
  __shared__ int    s_last;

  const int bid = blockIdx.x;
  const int tid = threadIdx.x;

  if (bid < NBLK_NOOBJ) {
    // ---------------- dense noobj iou-loss ----------------
    // Division-free ignore test: iou>=0.75 <=> 1.75*ai >= 0.75*(pa+ga)
    const int ba = bid % NBA;            // b*A + a
    const int by = bid / NBA;            // chunk index
    const int b  = ba / A, a = ba % A;
    if (tid < M) {
      const float* t = targ + (size_t)(b * M + tid) * TSTRIDE;
      float t0 = t[0], t1 = t[1], t2 = t[2], t3 = t[3], t4 = t[4], t5 = t[5];
      bool valid = (t0 + t1 + t2 + t3 + t4 + t5) > 0.0f;
      float gx = t0 * S, gy = t1 * S, gw = t2 * S, gh = t3 * S;
      float4 c;
      float ga;
      if (valid) {
        c = make_float4(gx - gw * 0.5f, gy - gh * 0.5f, gx + gw * 0.5f, gy + gh * 0.5f);
        ga = 0.75f * gw * gh;
      } else {
        c = make_float4(1e30f, 1e30f, -1e30f, -1e30f);   // never hits
        ga = 0.0f;
      }
      sgc[tid] = c;
      sga[tid] = ga;
    }
    __syncthreads();

    const float aw = anch[2 * a], ah = anch[2 * a + 1];
    const float* base = outp + (size_t)ba * CH * SS;
    const int pos0 = by * CHUNK + tid;

    float ptlx[POS_PER_T], ptly[POS_PER_T], pbrx[POS_PER_T], pbry[POS_PER_T];
    float rhsb[POS_PER_T], pcsq[POS_PER_T];
#pragma unroll
    for (int k = 0; k < POS_PER_T; ++k) {
      int pos = pos0 + k * 256;
      bool act = pos < SS;
      int p = act ? pos : 0;
      float tx = base[p];
      float ty = base[p + SS];
      float tw = base[p + 2 * SS];
      float th = base[p + 3 * SS];
      float tc = base[p + 4 * SS];
      int y = p / S, x = p - y * S;
      float px = sigm(tx) + (float)x;
      float py = sigm(ty) + (float)y;
      float pw = __expf(tw) * aw;
      float ph = __expf(th) * ah;
      ptlx[k] = px - pw * 0.5f;
      ptly[k] = py - ph * 0.5f;
      pbrx[k] = px + pw * 0.5f;
      pbry[k] = py + ph * 0.5f;
      rhsb[k] = 0.75f * (pw * ph);
      float pc = sigm(tc);
      pcsq[k] = act ? pc * pc : 0.0f;
    }

    int covered = 0;
    for (int m = 0; m < M; ++m) {
      float4 g = sgc[m];
      float ga = sga[m];
#pragma unroll
      for (int k = 0; k < POS_PER_T; ++k) {
        float tlx = fmaxf(ptlx[k], g.x);
        float tly = fmaxf(ptly[k], g.y);
        float brx = fminf(pbrx[k], g.z);
        float bry = fminf(pbry[k], g.w);
        float dx = brx - tlx;
        float dy = bry - tly;
        float ai = dx * dy;
        bool hit = (dx > 0.0f) & (dy > 0.0f) & (1.75f * ai >= rhsb[k] + ga);
        covered |= (hit ? 1 : 0) << k;
      }
    }

    float term = 0.0f;
#pragma unroll
    for (int k = 0; k < POS_PER_T; ++k)
      term += (covered >> k & 1) ? 0.0f : pcsq[k];

    for (int off = 32; off > 0; off >>= 1) term += __shfl_down(term, off);
    int lane = tid & 63, wid = tid >> 6;
    if (lane == 0) wsum[wid] = term;
    __syncthreads();
    if (tid == 0)
      blocksum[bid] = wsum[0] + wsum[1] + wsum[2] + wsum[3];
  } else {
    // ---------------- per-GT sparse corrections ----------------
    const int b = bid - NBLK_NOOBJ;
    const int m = tid;
    int valid = 0;
    float gx = 0, gy = 0, gw = 0, gh = 0;
    int gcls = 0, cx = 0, cy = 0, best = 0;
    float dxv = 0, dyv = 0, dwv = 0, dhv = 0;
    if (m < M) {
      const float* t = targ + (size_t)(b * M + m) * TSTRIDE;
      float t0 = t[0], t1 = t[1], t2 = t[2], t3 = t[3], t4 = t[4], t5 = t[5];
      valid = (t0 + t1 + t2 + t3 + t4 + t5) > 0.0f ? 1 : 0;
      gx = t0 * S; gy = t1 * S; gw = t2 * S; gh = t3 * S;
      gcls = (int)t5;
      sg[m][0] = gx; sg[m][1] = gy; sg[m][2] = gw; sg[m][3] = gh;
      sv[m] = valid;
    }
    if (valid) {
      cx = (int)fminf(fmaxf(floorf(gx - gw * 0.5f), 0.0f), (float)(S - 1));
      cy = (int)fminf(fmaxf(floorf(gy - gh * 0.5f), 0.0f), (float)(S - 1));
      float acx = cx + 0.5f, acy = cy + 0.5f;
      float bestv = -1.0f;
      for (int k = 0; k < A; ++k) {
        float aw = anch[2 * k], ah = anch[2 * k + 1];
        float tlx = fmaxf(acx - aw * 0.5f, gx - gw * 0.5f);
        float brx = fminf(acx + aw * 0.5f, gx + gw * 0.5f);
        float tly = fmaxf(acy - ah * 0.5f, gy - gh * 0.5f);
        float bry = fminf(acy + ah * 0.5f, gy + gh * 0.5f);
        float v = 0.0f;
        if (tlx < brx && tly < bry) {
          float ai = (brx - tlx) * (bry - tly);
          v = ai / (aw * ah + gw * gh - ai);
        }
        if (v > bestv) { bestv = v; best = k; }   // strict > == argmax first-max
      }
      dxv = gx - acx; dyv = gy - acy;
      dwv = gw / anch[2 * best]; dhv = gh / anch[2 * best + 1];
    }
    if (m < 64) skey[m] = valid ? ((cy * S + cx) * A + best) : -1;
    __syncthreads();
    // last-write-wins: winner iff no later valid gt hits same (cell, anchor)
    bool winner = (valid != 0);
    if (winner) {
      int key = skey[m];
      for (int mm = m + 1; mm < M; ++mm)
        if (skey[mm] == key) { winner = false; break; }
    }
    float ciou = 0.0f, cbox = 0.0f, ccls = 0.0f;
    if (winner) {
      int cell = cy * S + cx;
      const float* base = outp + (size_t)(b * A + best) * CH * SS + cell;
      float tx = base[0], ty = base[SS], tw = base[2 * SS], th = base[3 * SS], tc = base[4 * SS];
      float aw = anch[2 * best], ah = anch[2 * best + 1];
      float px = sigm(tx) + (float)cx;
      float py = sigm(ty) + (float)cy;
      float pw = __expf(tw) * aw;
      float ph = __expf(th) * ah;
      float miou = 0.0f;   // recompute max_iou at this single position
      for (int mm = 0; mm < M; ++mm)
        if (sv[mm])
          miou = fmaxf(miou, iou_one(px, py, pw, ph,
                                     sg[mm][0], sg[mm][1], sg[mm][2], sg[mm][3]));
      float pc = sigm(tc);
      float defterm = (miou >= IGNORE_T) ? 0.0f : pc * pc;
      float d5 = 5.0f * (pc - miou);                 // OBJ_SCALE = 5
      ciou = d5 * d5 - defterm;                      // replace default with obj term
      float e0 = sigm(tx) - dxv;
      float e1 = sigm(ty) - dyv;
      float e2 = __expf(tw) - dwv;
      float e3 = __expf(th) - dhv;
      cbox = e0 * e0 + e1 * e1 + e2 * e2 + e3 * e3;
      float l[NC];
      float lmax = -1e30f;
      for (int c = 0; c < NC; ++c) { l[c] = base[(5 + c) * SS]; lmax = fmaxf(lmax, l[c]); }
      float se = 0.0f;
      for (int c = 0; c < NC; ++c) se += __expf(l[c] - lmax);
      ccls = (lmax + __logf(se)) - l[gcls];          // NLL
    }
    if (m < 64) {       // all gt values live in wave 0 (M=50 < 64)
      for (int off = 32; off > 0; off >>= 1) {
        ciou += __shfl_down(ciou, off);
        cbox += __shfl_down(cbox, off);
        ccls += __shfl_down(ccls, off);
      }
      if (m == 0) {
        corr[b * 3 + 0] = ciou;
        corr[b * 3 + 1] = cbox;
        corr[b * 3 + 2] = ccls;
      }
    }
  }

  // ---------------- completion: last block reduces everything ----------------
  if (tid == 0) {
    __threadfence();                       // publish this block's partial
    int old = atomicAdd(counter, 1);       // device-scope
    s_last = (old == NBLK - 1) ? 1 : 0;
  }
  __syncthreads();
  if (s_last) {
    __threadfence();                       // acquire: see all partials
    float s = 0.0f;
    for (int i = tid; i < NBLK_NOOBJ; i += 256) s += blocksum[i];
    for (int off = 32; off > 0; off >>= 1) s += __shfl_down(s, off);
    int lane = tid & 63, wid = tid >> 6;
    if (lane == 0) wsum[wid] = s;
    __syncthreads();
    if (tid == 0) {
      float siou = wsum[0] + wsum[1] + wsum[2] + wsum[3];
      float cio = 0.0f, cbx = 0.0f, ccl = 0.0f;
#pragma unroll 8
      for (int bb = 0; bb < B; ++bb) {
        cio += corr[bb * 3 + 0];
        cbx += corr[bb * 3 + 1];
        ccl += corr[bb * 3 + 2];
      }
      // box: COORD/(2B) = 1/64 ; iou: 1/(2B) = 1/64 ; class: CLASS/B = 1/32
      out[0] = (siou + cio + cbx) * (1.0f / 64.0f) + ccl * (1.0f / 32.0f);
    }
  }
}

}  // namespace

extern "C" void kernel_launch(void* const* d_in, const int* in_sizes, int n_in,
                              void* d_out, int out_size, void* d_ws, size_t ws_size,
                              hipStream_t stream) {
  const float* outp = (const float*)d_in[0];
  const float* targ = (const float*)d_in[1];
  const float* anch = (const float*)d_in[2];
  int* counter = (int*)d_ws;                       // ws[0..3]: arrival counter
  float* blocksum = (float*)d_ws + 4;              // 16B-aligned partials
  float* corr = blocksum + NBLK_NOOBJ;             // B*3 per-batch corrections

  hipMemsetAsync(d_ws, 0, 4, stream);              // zero the counter each replay
  k_fused<<<NBLK, 256, 0, stream>>>(outp, targ, anch, counter, blocksum, corr,
                                    (float*)d_out);
}

// Round 4
// 29.487 us; speedup vs baseline: 1.4108x; 1.2094x over previous
//
#include <hip/hip_runtime.h>
#include <math.h>

namespace {
constexpr int S  = 52;
constexpr int SS = S * S;          // 2704
constexpr int A  = 5;
constexpr int NC = 20;
constexpr int CH = 5 + NC;         // 25
constexpr int B  = 32;
constexpr int M  = 50;
constexpr int TSTRIDE = 6;         // xy(2)+wh(2)+conf(1)+cls(1)
constexpr float IGNORE_T = 0.75f;

constexpr int POS_PER_T = 4;
constexpr int CHUNK = 256 * POS_PER_T;                 // 1024 positions per block
constexpr int NBY = (SS + CHUNK - 1) / CHUNK;          // 3
constexpr int NBA = B * A;                             // 160
constexpr int NBLK_NOOBJ = NBA * NBY;                  // 480
constexpr int NBLK = NBLK_NOOBJ + B;                   // 512 total blocks

__device__ __forceinline__ float sigm(float x) { return 1.0f / (1.0f + __expf(-x)); }

__device__ __forceinline__ float iou_one(float px, float py, float pw, float ph,
                                         float gx, float gy, float gw, float gh) {
  float tlx = fmaxf(px - pw * 0.5f, gx - gw * 0.5f);
  float brx = fminf(px + pw * 0.5f, gx + gw * 0.5f);
  float tly = fmaxf(py - ph * 0.5f, gy - gh * 0.5f);
  float bry = fminf(py + ph * 0.5f, gy + gh * 0.5f);
  if (tlx < brx && tly < bry) {
    float ai = (brx - tlx) * (bry - tly);
    return ai / (pw * ph + gw * gh - ai);
  }
  return 0.0f;
}

// Single kernel, no completion barrier: every block atomically adds its
// pre-scaled partial into out[0] (zeroed by a 4-byte memset node each replay).
__global__ __launch_bounds__(256) void k_fused(const float* __restrict__ outp,
                                               const float* __restrict__ targ,
                                               const float* __restrict__ anch,
                                               float* __restrict__ out) {
  __shared__ float4 sgc[M];
  __shared__ float  sga[M];
  __shared__ float  sg[M][4];
  __shared__ int    sv[M];
  __shared__ int    skey[64];
  __shared__ float  wsum[4];

  const int bid = blockIdx.x;
  const int tid = threadIdx.x;

  if (bid < NBLK_NOOBJ) {
    // ---------------- dense noobj iou-loss ----------------
    // Division-free ignore test: iou>=0.75 <=> 1.75*ai >= 0.75*(pa+ga)
    const int ba = bid % NBA;            // b*A + a
    const int by = bid / NBA;            // chunk index
    const int b  = ba / A, a = ba % A;
    if (tid < M) {
      const float* t = targ + (size_t)(b * M + tid) * TSTRIDE;
      float t0 = t[0], t1 = t[1], t2 = t[2], t3 = t[3], t4 = t[4], t5 = t[5];
      bool valid = (t0 + t1 + t2 + t3 + t4 + t5) > 0.0f;
      float gx = t0 * S, gy = t1 * S, gw = t2 * S, gh = t3 * S;
      float4 c;
      float ga;
      if (valid) {
        c = make_float4(gx - gw * 0.5f, gy - gh * 0.5f, gx + gw * 0.5f, gy + gh * 0.5f);
        ga = 0.75f * gw * gh;
      } else {
        c = make_float4(1e30f, 1e30f, -1e30f, -1e30f);   // never hits
        ga = 0.0f;
      }
      sgc[tid] = c;
      sga[tid] = ga;
    }
    __syncthreads();

    const float aw = anch[2 * a], ah = anch[2 * a + 1];
    const float* base = outp + (size_t)ba * CH * SS;
    const int pos0 = by * CHUNK + tid;

    float ptlx[POS_PER_T], ptly[POS_PER_T], pbrx[POS_PER_T], pbry[POS_PER_T];
    float rhsb[POS_PER_T], pcsq[POS_PER_T];
#pragma unroll
    for (int k = 0; k < POS_PER_T; ++k) {
      int pos = pos0 + k * 256;
      bool act = pos < SS;
      int p = act ? pos : 0;
      float tx = base[p];
      float ty = base[p + SS];
      float tw = base[p + 2 * SS];
      float th = base[p + 3 * SS];
      float tc = base[p + 4 * SS];
      int y = p / S, x = p - y * S;
      float px = sigm(tx) + (float)x;
      float py = sigm(ty) + (float)y;
      float pw = __expf(tw) * aw;
      float ph = __expf(th) * ah;
      ptlx[k] = px - pw * 0.5f;
      ptly[k] = py - ph * 0.5f;
      pbrx[k] = px + pw * 0.5f;
      pbry[k] = py + ph * 0.5f;
      rhsb[k] = 0.75f * (pw * ph);
      float pc = sigm(tc);
      pcsq[k] = act ? pc * pc : 0.0f;
    }

    int covered = 0;
    for (int m = 0; m < M; ++m) {
      float4 g = sgc[m];
      float ga = sga[m];
#pragma unroll
      for (int k = 0; k < POS_PER_T; ++k) {
        float tlx = fmaxf(ptlx[k], g.x);
        float tly = fmaxf(ptly[k], g.y);
        float brx = fminf(pbrx[k], g.z);
        float bry = fminf(pbry[k], g.w);
        float dx = brx - tlx;
        float dy = bry - tly;
        float ai = dx * dy;
        bool hit = (dx > 0.0f) & (dy > 0.0f) & (1.75f * ai >= rhsb[k] + ga);
        covered |= (hit ? 1 : 0) << k;
      }
    }

    float term = 0.0f;
#pragma unroll
    for (int k = 0; k < POS_PER_T; ++k)
      term += (covered >> k & 1) ? 0.0f : pcsq[k];

    for (int off = 32; off > 0; off >>= 1) term += __shfl_down(term, off);
    int lane = tid & 63, wid = tid >> 6;
    if (lane == 0) wsum[wid] = term;
    __syncthreads();
    if (tid == 0)
      atomicAdd(out, (wsum[0] + wsum[1] + wsum[2] + wsum[3]) * (1.0f / 64.0f));
  } else {
    // ---------------- per-GT sparse corrections ----------------
    const int b = bid - NBLK_NOOBJ;
    const int m = tid;
    int valid = 0;
    float gx = 0, gy = 0, gw = 0, gh = 0;
    int gcls = 0, cx = 0, cy = 0, best = 0;
    float dxv = 0, dyv = 0, dwv = 0, dhv = 0;
    if (m < M) {
      const float* t = targ + (size_t)(b * M + m) * TSTRIDE;
      float t0 = t[0], t1 = t[1], t2 = t[2], t3 = t[3], t4 = t[4], t5 = t[5];
      valid = (t0 + t1 + t2 + t3 + t4 + t5) > 0.0f ? 1 : 0;
      gx = t0 * S; gy = t1 * S; gw = t2 * S; gh = t3 * S;
      gcls = (int)t5;
      sg[m][0] = gx; sg[m][1] = gy; sg[m][2] = gw; sg[m][3] = gh;
      sv[m] = valid;
    }
    if (valid) {
      cx = (int)fminf(fmaxf(floorf(gx - gw * 0.5f), 0.0f), (float)(S - 1));
      cy = (int)fminf(fmaxf(floorf(gy - gh * 0.5f), 0.0f), (float)(S - 1));
      float acx = cx + 0.5f, acy = cy + 0.5f;
      float bestv = -1.0f;
      for (int k = 0; k < A; ++k) {
        float aw = anch[2 * k], ah = anch[2 * k + 1];
        float tlx = fmaxf(acx - aw * 0.5f, gx - gw * 0.5f);
        float brx = fminf(acx + aw * 0.5f, gx + gw * 0.5f);
        float tly = fmaxf(acy - ah * 0.5f, gy - gh * 0.5f);
        float bry = fminf(acy + ah * 0.5f, gy + gh * 0.5f);
        float v = 0.0f;
        if (tlx < brx && tly < bry) {
          float ai = (brx - tlx) * (bry - tly);
          v = ai / (aw * ah + gw * gh - ai);
        }
        if (v > bestv) { bestv = v; best = k; }   // strict > == argmax first-max
      }
      dxv = gx - acx; dyv = gy - acy;
      dwv = gw / anch[2 * best]; dhv = gh / anch[2 * best + 1];
    }
    if (m < 64) skey[m] = valid ? ((cy * S + cx) * A + best) : -1;
    __syncthreads();
    // last-write-wins: winner iff no later valid gt hits same (cell, anchor)
    bool winner = (valid != 0);
    if (winner) {
      int key = skey[m];
      for (int mm = m + 1; mm < M; ++mm)
        if (skey[mm] == key) { winner = false; break; }
    }
    float ciou = 0.0f, cbox = 0.0f, ccls = 0.0f;
    if (winner) {
      int cell = cy * S + cx;
      const float* base = outp + (size_t)(b * A + best) * CH * SS + cell;
      float tx = base[0], ty = base[SS], tw = base[2 * SS], th = base[3 * SS], tc = base[4 * SS];
      float aw = anch[2 * best], ah = anch[2 * best + 1];
      float px = sigm(tx) + (float)cx;
      float py = sigm(ty) + (float)cy;
      float pw = __expf(tw) * aw;
      float ph = __expf(th) * ah;
      float miou = 0.0f;   // recompute max_iou at this single position
      for (int mm = 0; mm < M; ++mm)
        if (sv[mm])
          miou = fmaxf(miou, iou_one(px, py, pw, ph,
                                     sg[mm][0], sg[mm][1], sg[mm][2], sg[mm][3]));
      float pc = sigm(tc);
      float defterm = (miou >= IGNORE_T) ? 0.0f : pc * pc;
      float d5 = 5.0f * (pc - miou);                 // OBJ_SCALE = 5
      ciou = d5 * d5 - defterm;                      // replace default with obj term
      float e0 = sigm(tx) - dxv;
      float e1 = sigm(ty) - dyv;
      float e2 = __expf(tw) - dwv;
      float e3 = __expf(th) - dhv;
      cbox = e0 * e0 + e1 * e1 + e2 * e2 + e3 * e3;
      float l[NC];
      float lmax = -1e30f;
      for (int c = 0; c < NC; ++c) { l[c] = base[(5 + c) * SS]; lmax = fmaxf(lmax, l[c]); }
      float se = 0.0f;
      for (int c = 0; c < NC; ++c) se += __expf(l[c] - lmax);
      ccls = (lmax + __logf(se)) - l[gcls];          // NLL
    }
    if (m < 64) {       // all gt values live in wave 0 (M=50 < 64)
      for (int off = 32; off > 0; off >>= 1) {
        ciou += __shfl_down(ciou, off);
        cbox += __shfl_down(cbox, off);
        ccls += __shfl_down(ccls, off);
      }
      // box: COORD/(2B) = 1/64 ; iou: 1/(2B) = 1/64 ; class: CLASS/B = 1/32
      if (m == 0)
        atomicAdd(out, (ciou + cbox) * (1.0f / 64.0f) + ccls * (1.0f / 32.0f));
    }
  }
}

}  // namespace

extern "C" void kernel_launch(void* const* d_in, const int* in_sizes, int n_in,
                              void* d_out, int out_size, void* d_ws, size_t ws_size,
                              hipStream_t stream) {
  const float* outp = (const float*)d_in[0];
  const float* targ = (const float*)d_in[1];
  const float* anch = (const float*)d_in[2];

  hipMemsetAsync(d_out, 0, 4, stream);   // zero the scalar accumulator each replay
  k_fused<<<NBLK, 256, 0, stream>>>(outp, targ, anch, (float*)d_out);
}